// Round 10
// baseline (136.203 us; speedup 1.0000x reference)
//
#include <hip/hip_runtime.h>
#include <hip/hip_bf16.h>
#include <cstdint>

#define EPS 1e-5f

typedef short bf16x8 __attribute__((ext_vector_type(8)));
typedef float f32x16 __attribute__((ext_vector_type(16)));
typedef unsigned int u32x4 __attribute__((ext_vector_type(4)));

// ws float-offsets
#define WS_TW1S 0       // 16384 ushort: chi-permuted GEMM2 A-frag layout
#define WS_FWQ  8192    // 8192 ushort: GEMM1 A-frag layout [((ks*2+h)*64 + hc)*8 + jj]
#define WS_TB1Q 12288   // 256 floats: [(t*2+hi)*16 + q]
#define WS_W2Q  12544   // 256 floats: [(t*2+hi)*16 + q]
#define WS_FBQ  12800   // 64 floats:  [hi*32 + ht*16 + q]
#define WS_C2   12864   // 8 floats
#define WS_BENCH 262144 // diagnostic sentinel region (1 MB offset, ws is >=512MB)

static __device__ __forceinline__ unsigned short f2bf(float f) {
    unsigned int u = __float_as_uint(f);
    u += 0x7fffu + ((u >> 16) & 1u);   // RNE
    return (unsigned short)(u >> 16);
}
static __device__ __forceinline__ short f2bf_fast(float f) {
    __hip_bfloat16 b = __float2bfloat16(f);
    return __builtin_bit_cast(short, b);
}
static __device__ __forceinline__ unsigned pk_bf16(float lo, float hi) {
    unsigned l = (unsigned)(unsigned short)__builtin_bit_cast(unsigned short, __float2bfloat16(lo));
    unsigned h = (unsigned)(unsigned short)__builtin_bit_cast(unsigned short, __float2bfloat16(hi));
    return l | (h << 16);
}

// Fold both eval-mode BNs; emit bf16 weights in frag-native layouts.
// chi: channel j = ht*32+qq*8+4h+m -> ks = ht*2+(qq>>1), slot = 8h+(qq&1)*4+m
__global__ void tarnet_pre(
    const float* __restrict__ fw, const float* __restrict__ fb,
    const float* __restrict__ f_gamma, const float* __restrict__ f_beta,
    const float* __restrict__ f_mean,  const float* __restrict__ f_var,
    const float* __restrict__ tw1, const float* __restrict__ tb1,
    const float* __restrict__ t_gamma, const float* __restrict__ t_beta,
    const float* __restrict__ t_mean,  const float* __restrict__ t_var,
    const float* __restrict__ tw2, const float* __restrict__ tb2,
    float* __restrict__ ws)
{
    __shared__ float fs[64], fsh[64];
    const int i = threadIdx.x;  // 256 threads
    if (i < 64) {
        float s = f_gamma[i] * rsqrtf(f_var[i] + EPS);
        fs[i]  = s;
        fsh[i] = f_beta[i] - f_mean[i] * s;
    }
    __syncthreads();

    unsigned short* tw1s_u = (unsigned short*)(ws + WS_TW1S);
    unsigned short* fwq_u  = (unsigned short*)(ws + WS_FWQ);

    const int t = i >> 5, r = i & 31;
    const int idx = t * 32 + r;
    {
        float tsc  = t_gamma[idx] * rsqrtf(t_var[idx] + EPS);
        float w2s  = tw2[idx] * tsc;
        float tb1s = tb1[idx];
        for (int j = 0; j < 64; ++j) {
            float w = tw1[idx * 64 + j];
            tb1s += w * fsh[j];
            int ht = j >> 5, qq = (j >> 3) & 3, h = (j >> 2) & 1, m = j & 3;
            int ks = ht * 2 + (qq >> 1);
            int ep = (qq & 1) * 4 + m;
            tw1s_u[(((t*4 + ks)*2 + h)*32 + r)*8 + ep] = f2bf(w * fs[j]);
        }
        int q  = ((r >> 3) << 2) | (r & 3);
        int hq = (r >> 2) & 1;
        ws[WS_TB1Q + (t*2 + hq)*16 + q] = tb1s;
        ws[WS_W2Q  + (t*2 + hq)*16 + q] = w2s;
    }
    if (r == 0) {
        float a = tb2[t];
        for (int rr = 0; rr < 32; ++rr) {
            int id2 = t*32 + rr;
            float ts2 = t_gamma[id2] * rsqrtf(t_var[id2] + EPS);
            a += tw2[id2] * (t_beta[id2] - ts2 * t_mean[id2]);
        }
        ws[WS_C2 + t] = a;
    }
    {   // fw conversion parallelized across all 256 threads
        const int hc = i >> 2, kq = (i & 3) * 32;
        for (int kk = 0; kk < 32; ++kk) {
            const int k = kq + kk;
            const int ks = k >> 4, h = (k >> 3) & 1, jj = k & 7;
            fwq_u[(((ks*2 + h)*64) + hc)*8 + jj] = f2bf(fw[hc*128 + k]);
        }
    }
    if (i < 64) {
        int ht = i >> 5, r32 = i & 31;
        int q  = ((r32 >> 3) << 2) | (r32 & 3);
        int hq = (r32 >> 2) & 1;
        ws[WS_FBQ + hq*32 + ht*16 + q] = fb[i];
    }
}

// ---- DIAGNOSTIC: pure coalesced x read, 4 full passes, m13/fillBuffer shape ----
// 512 blocks x 256 thr, grid-stride, 32 B/lane/iter, 16 loads in flight.
#define NSB 512
__global__ __launch_bounds__(256) void x_stream_bench(
    const float* __restrict__ x, float* __restrict__ wsf)
{
    const int gid = blockIdx.x * 256 + threadIdx.x;   // 131072 threads
    const float4* xq = (const float4*)x;              // 8388608 float4
    float4 a0 = {0,0,0,0}, a1 = {0,0,0,0}, a2 = {0,0,0,0}, a3 = {0,0,0,0};
#pragma unroll 1
    for (int pass = 0; pass < 4; ++pass) {
#pragma unroll 8
        for (int it = 0; it < 32; ++it) {
            const size_t base = ((size_t)it * 131072 + gid) * 2;
            float4 u = xq[base], v = xq[base + 1];
            if (it & 1) {
                a0.x += u.x; a0.y += u.y; a0.z += u.z; a0.w += u.w;
                a1.x += v.x; a1.y += v.y; a1.z += v.z; a1.w += v.w;
            } else {
                a2.x += u.x; a2.y += u.y; a2.z += u.z; a2.w += u.w;
                a3.x += v.x; a3.y += v.y; a3.z += v.z; a3.w += v.w;
            }
        }
    }
    wsf[WS_BENCH + gid] = (a0.x + a0.y + a0.z + a0.w) + (a1.x + a1.y + a1.z + a1.w)
                        + (a2.x + a2.y + a2.z + a2.w) + (a3.x + a3.y + a3.z + a3.w);
}

// ---- main: EXACT R8 (56 us champion). 4 waves/block, x coalesced-staged LDS. ----
__global__ __launch_bounds__(256, 2) void tarnet_main(
    const float* __restrict__ x, const int* __restrict__ t_arr,
    const float* __restrict__ ws, float* __restrict__ out)
{
    __shared__ unsigned short x_lds_u[256 * 128];   // 64 KB bf16, XOR-swizzled
    char* xl = (char*)x_lds_u;

    const int tid  = threadIdx.x;
    const int wave = tid >> 6, lane = tid & 63;
    const int ln31 = lane & 31, hi = lane >> 5;
    const int sbase = blockIdx.x * 256;

    {
        const float4* xg = (const float4*)(x + (size_t)sbase * 128);
#pragma unroll
        for (int it = 0; it < 16; ++it) {
            const int i = it * 256 + tid;
            float4 a = xg[2*i], b = xg[2*i + 1];
            bf16x8 v;
            v[0] = f2bf_fast(a.x); v[1] = f2bf_fast(a.y);
            v[2] = f2bf_fast(a.z); v[3] = f2bf_fast(a.w);
            v[4] = f2bf_fast(b.x); v[5] = f2bf_fast(b.y);
            v[6] = f2bf_fast(b.z); v[7] = f2bf_fast(b.w);
            const int row = i >> 4, pcol = i & 15;
            const int addr = row * 256 + ((pcol * 16) ^ ((row & 15) << 4));
            *(bf16x8*)(xl + addr) = v;
        }
    }
    __syncthreads();

    const unsigned short* fwq_u  = (const unsigned short*)(ws + WS_FWQ);
    const unsigned short* tw1s_u = (const unsigned short*)(ws + WS_TW1S);

    const int tsel0 = t_arr[sbase + wave * 64 + ln31];
    const int tsel1 = t_arr[sbase + wave * 64 + 32 + ln31];

    const int srow0 = wave * 64 + ln31;
    const int srow1 = srow0 + 32;
    const int rb0 = srow0 * 256, xr0 = (srow0 & 15) << 4;
    const int rb1 = srow1 * 256, xr1 = (srow1 & 15) << 4;

    f32x16 acc[2][2];   // [st][ht]
    {
        const float* fbq = ws + WS_FBQ;
#pragma unroll
        for (int ht = 0; ht < 2; ++ht)
#pragma unroll
            for (int q = 0; q < 16; ++q) {
                float v = fbq[hi*32 + ht*16 + q];
                acc[0][ht][q] = v;
                acc[1][ht][q] = v;
            }
    }
#pragma unroll
    for (int ks = 0; ks < 8; ++ks) {
        bf16x8 wa0 = *(const bf16x8*)(fwq_u + (((ks*2 + hi)*64) + ln31     )*8);
        bf16x8 wa1 = *(const bf16x8*)(fwq_u + (((ks*2 + hi)*64) + ln31 + 32)*8);
        const int c = ks*32 + hi*16;
        bf16x8 xf0 = *(const bf16x8*)(xl + rb0 + (c ^ xr0));
        bf16x8 xf1 = *(const bf16x8*)(xl + rb1 + (c ^ xr1));
        acc[0][0] = __builtin_amdgcn_mfma_f32_32x32x16_bf16(wa0, xf0, acc[0][0], 0, 0, 0);
        acc[0][1] = __builtin_amdgcn_mfma_f32_32x32x16_bf16(wa1, xf0, acc[0][1], 0, 0, 0);
        acc[1][0] = __builtin_amdgcn_mfma_f32_32x32x16_bf16(wa0, xf1, acc[1][0], 0, 0, 0);
        acc[1][1] = __builtin_amdgcn_mfma_f32_32x32x16_bf16(wa1, xf1, acc[1][1], 0, 0, 0);
    }

    bf16x8 hb[2][4];   // [st][ks]
#pragma unroll
    for (int st = 0; st < 2; ++st) {
        unsigned w0[2][4], w1[2][4];
#pragma unroll
        for (int ht = 0; ht < 2; ++ht)
#pragma unroll
            for (int qq = 0; qq < 4; ++qq) {
                float a0 = fmaxf(acc[st][ht][qq*4+0], 0.f);
                float a1 = fmaxf(acc[st][ht][qq*4+1], 0.f);
                float a2 = fmaxf(acc[st][ht][qq*4+2], 0.f);
                float a3 = fmaxf(acc[st][ht][qq*4+3], 0.f);
                w0[ht][qq] = pk_bf16(a0, a1);
                w1[ht][qq] = pk_bf16(a2, a3);
            }
#pragma unroll
        for (int ks = 0; ks < 4; ++ks) {
            const int ht = ks >> 1, qa = (ks & 1) * 2;
            u32x4 wv = {w0[ht][qa], w1[ht][qa], w0[ht][qa+1], w1[ht][qa+1]};
            hb[st][ks] = __builtin_bit_cast(bf16x8, wv);
        }
    }

    float out0 = 0.f, out1 = 0.f;
#pragma unroll 2
    for (int th = 0; th < 8; ++th) {
        bf16x8 aw[4];
#pragma unroll
        for (int ks = 0; ks < 4; ++ks)
            aw[ks] = *(const bf16x8*)(tw1s_u + (((th*4 + ks)*2 + hi)*32 + ln31)*8);
        float4 tb4[4], w24[4];
#pragma unroll
        for (int i2 = 0; i2 < 4; ++i2) {
            tb4[i2] = ((const float4*)(ws + WS_TB1Q))[(th*2 + hi)*4 + i2];
            w24[i2] = ((const float4*)(ws + WS_W2Q))[(th*2 + hi)*4 + i2];
        }
        const float c2t = ws[WS_C2 + th];
#pragma unroll
        for (int st = 0; st < 2; ++st) {
            f32x16 z;
#pragma unroll
            for (int q = 0; q < 16; ++q) z[q] = ((const float*)tb4)[q];
            z = __builtin_amdgcn_mfma_f32_32x32x16_bf16(aw[0], hb[st][0], z, 0, 0, 0);
            z = __builtin_amdgcn_mfma_f32_32x32x16_bf16(aw[1], hb[st][1], z, 0, 0, 0);
            z = __builtin_amdgcn_mfma_f32_32x32x16_bf16(aw[2], hb[st][2], z, 0, 0, 0);
            z = __builtin_amdgcn_mfma_f32_32x32x16_bf16(aw[3], hb[st][3], z, 0, 0, 0);
            float p0 = 0.f, p1 = 0.f, p2 = 0.f, p3 = 0.f;
#pragma unroll
            for (int q = 0; q < 4; ++q) {
                p0 = fmaf(((const float*)w24)[q],    fmaxf(z[q],    0.f), p0);
                p1 = fmaf(((const float*)w24)[q+4],  fmaxf(z[q+4],  0.f), p1);
                p2 = fmaf(((const float*)w24)[q+8],  fmaxf(z[q+8],  0.f), p2);
                p3 = fmaf(((const float*)w24)[q+12], fmaxf(z[q+12], 0.f), p3);
            }
            float p = (p0 + p1) + (p2 + p3);
            p += __shfl_xor(p, 32);
            p += c2t;
            if (st == 0) out0 = (th == tsel0) ? p : out0;
            else         out1 = (th == tsel1) ? p : out1;
        }
    }
    out[sbase + wave * 64 + lane] = hi ? out1 : out0;
}

extern "C" void kernel_launch(void* const* d_in, const int* in_sizes, int n_in,
                              void* d_out, int out_size, void* d_ws, size_t ws_size,
                              hipStream_t stream) {
    const float* x       = (const float*)d_in[0];
    const int*   t       = (const int*)  d_in[1];
    const float* fw      = (const float*)d_in[2];
    const float* fb      = (const float*)d_in[3];
    const float* f_gamma = (const float*)d_in[4];
    const float* f_beta  = (const float*)d_in[5];
    const float* f_mean  = (const float*)d_in[6];
    const float* f_var   = (const float*)d_in[7];
    const float* tw1     = (const float*)d_in[8];
    const float* tb1     = (const float*)d_in[9];
    const float* t_gamma = (const float*)d_in[10];
    const float* t_beta  = (const float*)d_in[11];
    const float* t_mean  = (const float*)d_in[12];
    const float* t_var   = (const float*)d_in[13];
    const float* tw2     = (const float*)d_in[14];
    const float* tb2     = (const float*)d_in[15];

    float* ws   = (float*)d_ws;
    float* outp = (float*)d_out;
    const int B = in_sizes[0] / 128;   // 262144

    tarnet_pre<<<1, 256, 0, stream>>>(fw, fb, f_gamma, f_beta, f_mean, f_var,
                                      tw1, tb1, t_gamma, t_beta, t_mean, t_var,
                                      tw2, tb2, ws);
    x_stream_bench<<<NSB, 256, 0, stream>>>(x, ws);
    tarnet_main<<<B / 256, 256, 0, stream>>>(x, t, ws, outp);
}

// Round 11
// 77.113 us; speedup vs baseline: 1.7663x; 1.7663x over previous
//
#include <hip/hip_runtime.h>
#include <hip/hip_bf16.h>
#include <cstdint>

#define EPS 1e-5f

typedef short bf16x8 __attribute__((ext_vector_type(8)));
typedef float f32x16 __attribute__((ext_vector_type(16)));
typedef unsigned int u32x4 __attribute__((ext_vector_type(4)));

// ws float-offsets
#define WS_TW1S 0       // 16384 ushort: chi-permuted GEMM2 A-frag layout
#define WS_FWQ  8192    // 8192 ushort: GEMM1 A-frag layout [((ks*2+h)*64 + hc)*8 + jj]
#define WS_TB1Q 12288   // 256 floats: [(t*2+hi)*16 + q]
#define WS_W2Q  12544   // 256 floats: [(t*2+hi)*16 + q]
#define WS_FBQ  12800   // 64 floats:  [hi*32 + ht*16 + q]
#define WS_C2   12864   // 8 floats
#define WS_BENCH 262144 // diagnostic sentinel region

static __device__ __forceinline__ unsigned short f2bf(float f) {
    unsigned int u = __float_as_uint(f);
    u += 0x7fffu + ((u >> 16) & 1u);   // RNE
    return (unsigned short)(u >> 16);
}
static __device__ __forceinline__ short f2bf_fast(float f) {
    __hip_bfloat16 b = __float2bfloat16(f);
    return __builtin_bit_cast(short, b);
}
static __device__ __forceinline__ unsigned pk_bf16(float lo, float hi) {
    unsigned l = (unsigned)(unsigned short)__builtin_bit_cast(unsigned short, __float2bfloat16(lo));
    unsigned h = (unsigned)(unsigned short)__builtin_bit_cast(unsigned short, __float2bfloat16(hi));
    return l | (h << 16);
}

// Fold both eval-mode BNs; emit bf16 weights in frag-native layouts.
// chi: channel j = ht*32+qq*8+4h+m -> ks = ht*2+(qq>>1), slot = 8h+(qq&1)*4+m
__global__ void tarnet_pre(
    const float* __restrict__ fw, const float* __restrict__ fb,
    const float* __restrict__ f_gamma, const float* __restrict__ f_beta,
    const float* __restrict__ f_mean,  const float* __restrict__ f_var,
    const float* __restrict__ tw1, const float* __restrict__ tb1,
    const float* __restrict__ t_gamma, const float* __restrict__ t_beta,
    const float* __restrict__ t_mean,  const float* __restrict__ t_var,
    const float* __restrict__ tw2, const float* __restrict__ tb2,
    float* __restrict__ ws)
{
    __shared__ float fs[64], fsh[64];
    const int i = threadIdx.x;  // 256 threads
    if (i < 64) {
        float s = f_gamma[i] * rsqrtf(f_var[i] + EPS);
        fs[i]  = s;
        fsh[i] = f_beta[i] - f_mean[i] * s;
    }
    __syncthreads();

    unsigned short* tw1s_u = (unsigned short*)(ws + WS_TW1S);
    unsigned short* fwq_u  = (unsigned short*)(ws + WS_FWQ);

    const int t = i >> 5, r = i & 31;
    const int idx = t * 32 + r;
    {
        float tsc  = t_gamma[idx] * rsqrtf(t_var[idx] + EPS);
        float w2s  = tw2[idx] * tsc;
        float tb1s = tb1[idx];
        for (int j = 0; j < 64; ++j) {
            float w = tw1[idx * 64 + j];
            tb1s += w * fsh[j];
            int ht = j >> 5, qq = (j >> 3) & 3, h = (j >> 2) & 1, m = j & 3;
            int ks = ht * 2 + (qq >> 1);
            int ep = (qq & 1) * 4 + m;
            tw1s_u[(((t*4 + ks)*2 + h)*32 + r)*8 + ep] = f2bf(w * fs[j]);
        }
        int q  = ((r >> 3) << 2) | (r & 3);
        int hq = (r >> 2) & 1;
        ws[WS_TB1Q + (t*2 + hq)*16 + q] = tb1s;
        ws[WS_W2Q  + (t*2 + hq)*16 + q] = w2s;
    }
    if (r == 0) {
        float a = tb2[t];
        for (int rr = 0; rr < 32; ++rr) {
            int id2 = t*32 + rr;
            float ts2 = t_gamma[id2] * rsqrtf(t_var[id2] + EPS);
            a += tw2[id2] * (t_beta[id2] - ts2 * t_mean[id2]);
        }
        ws[WS_C2 + t] = a;
    }
    {   // fw conversion parallelized across all 256 threads
        const int hc = i >> 2, kq = (i & 3) * 32;
        for (int kk = 0; kk < 32; ++kk) {
            const int k = kq + kk;
            const int ks = k >> 4, h = (k >> 3) & 1, jj = k & 7;
            fwq_u[(((ks*2 + h)*64) + hc)*8 + jj] = f2bf(fw[hc*128 + k]);
        }
    }
    if (i < 64) {
        int ht = i >> 5, r32 = i & 31;
        int q  = ((r32 >> 3) << 2) | (r32 & 3);
        int hq = (r32 >> 2) & 1;
        ws[WS_FBQ + hq*32 + ht*16 + q] = fb[i];
    }
}

// ---- DIAGNOSTIC: staging ONLY (load + cvt + swizzled ds_write), 1 pass of x ----
__global__ __launch_bounds__(256) void x_stage_probe(
    const float* __restrict__ x, float* __restrict__ wsf)
{
    __shared__ unsigned short xls[128 * 128];   // 32 KB, same layout as main
    char* xl = (char*)xls;
    const int tid = threadIdx.x;
    const float4* xg = (const float4*)(x + (size_t)blockIdx.x * 16384);
#pragma unroll 2
    for (int it = 0; it < 8; ++it) {
        const int i = it * 256 + tid;
        float4 a = xg[2*i], b = xg[2*i + 1];
        bf16x8 v;
        v[0] = f2bf_fast(a.x); v[1] = f2bf_fast(a.y);
        v[2] = f2bf_fast(a.z); v[3] = f2bf_fast(a.w);
        v[4] = f2bf_fast(b.x); v[5] = f2bf_fast(b.y);
        v[6] = f2bf_fast(b.z); v[7] = f2bf_fast(b.w);
        const int row = i >> 4, pcol = i & 15;
        *(bf16x8*)(xl + row * 256 + ((pcol * 16) ^ ((row & 15) << 4))) = v;
    }
    __syncthreads();
    // consume so nothing is DCE'd
    u32x4 r = *(const u32x4*)(xl + tid * 16);
    wsf[WS_BENCH + blockIdx.x * 256 + tid] = __int_as_float((int)(r[0] + r[1] + r[2] + r[3]));
}

// ---- main: compact 128-sample tile (32 KB LDS) -> 4+ blocks/CU phase overlap ----
__global__ __launch_bounds__(256, 4) void tarnet_main(
    const float* __restrict__ x, const int* __restrict__ t_arr,
    const float* __restrict__ ws, float* __restrict__ out)
{
    __shared__ unsigned short x_lds_u[128 * 128];   // 32 KB bf16, XOR-swizzled
    char* xl = (char*)x_lds_u;

    const int tid  = threadIdx.x;
    const int wave = tid >> 6, lane = tid & 63;
    const int ln31 = lane & 31, hi = lane >> 5;
    const int sbase = blockIdx.x * 128;

    {   // coalesced stage: 8 iters x 32 B/lane contiguous
        const float4* xg = (const float4*)(x + (size_t)sbase * 128);
#pragma unroll 2
        for (int it = 0; it < 8; ++it) {
            const int i = it * 256 + tid;
            float4 a = xg[2*i], b = xg[2*i + 1];
            bf16x8 v;
            v[0] = f2bf_fast(a.x); v[1] = f2bf_fast(a.y);
            v[2] = f2bf_fast(a.z); v[3] = f2bf_fast(a.w);
            v[4] = f2bf_fast(b.x); v[5] = f2bf_fast(b.y);
            v[6] = f2bf_fast(b.z); v[7] = f2bf_fast(b.w);
            const int row = i >> 4, pcol = i & 15;
            *(bf16x8*)(xl + row * 256 + ((pcol * 16) ^ ((row & 15) << 4))) = v;
        }
    }
    __syncthreads();

    const unsigned short* fwq_u  = (const unsigned short*)(ws + WS_FWQ);
    const unsigned short* tw1s_u = (const unsigned short*)(ws + WS_TW1S);

    const int tsel = t_arr[sbase + wave * 32 + ln31];

    // this lane's sample row in LDS
    const int srow = wave * 32 + ln31;
    const int rb = srow * 256, swz = (srow & 15) << 4;

    // ---- GEMM1: h^T = fw @ x^T (+fb), rows=hc, cols=32 samples ----
    f32x16 acc[2];   // [ht]
    {
        const float* fbq = ws + WS_FBQ;
#pragma unroll
        for (int ht = 0; ht < 2; ++ht)
#pragma unroll
            for (int q = 0; q < 16; ++q)
                acc[ht][q] = fbq[hi*32 + ht*16 + q];
    }
#pragma unroll
    for (int ks = 0; ks < 8; ++ks) {
        bf16x8 wa0 = *(const bf16x8*)(fwq_u + (((ks*2 + hi)*64) + ln31     )*8);
        bf16x8 wa1 = *(const bf16x8*)(fwq_u + (((ks*2 + hi)*64) + ln31 + 32)*8);
        bf16x8 xf  = *(const bf16x8*)(xl + rb + ((ks*32 + hi*16) ^ swz));
        acc[0] = __builtin_amdgcn_mfma_f32_32x32x16_bf16(wa0, xf, acc[0], 0, 0, 0);
        acc[1] = __builtin_amdgcn_mfma_f32_32x32x16_bf16(wa1, xf, acc[1], 0, 0, 0);
    }

    // ---- relu -> bf16 pack: lane-local B-frags under chi ----
    bf16x8 hb[4];
    {
        unsigned w0[2][4], w1[2][4];
#pragma unroll
        for (int ht = 0; ht < 2; ++ht)
#pragma unroll
            for (int qq = 0; qq < 4; ++qq) {
                float a0 = fmaxf(acc[ht][qq*4+0], 0.f);
                float a1 = fmaxf(acc[ht][qq*4+1], 0.f);
                float a2 = fmaxf(acc[ht][qq*4+2], 0.f);
                float a3 = fmaxf(acc[ht][qq*4+3], 0.f);
                w0[ht][qq] = pk_bf16(a0, a1);
                w1[ht][qq] = pk_bf16(a2, a3);
            }
#pragma unroll
        for (int ks = 0; ks < 4; ++ks) {
            const int ht = ks >> 1, qa = (ks & 1) * 2;
            u32x4 wv = {w0[ht][qa], w1[ht][qa], w0[ht][qa+1], w1[ht][qa+1]};
            hb[ks] = __builtin_bit_cast(bf16x8, wv);
        }
    }

    // ---- GEMM2 dense over 8 heads ----
    float outv = 0.f;
#pragma unroll 2
    for (int th = 0; th < 8; ++th) {
        bf16x8 aw[4];
#pragma unroll
        for (int ks = 0; ks < 4; ++ks)
            aw[ks] = *(const bf16x8*)(tw1s_u + (((th*4 + ks)*2 + hi)*32 + ln31)*8);
        float4 tb4[4], w24[4];
#pragma unroll
        for (int i2 = 0; i2 < 4; ++i2) {
            tb4[i2] = ((const float4*)(ws + WS_TB1Q))[(th*2 + hi)*4 + i2];
            w24[i2] = ((const float4*)(ws + WS_W2Q))[(th*2 + hi)*4 + i2];
        }
        const float c2t = ws[WS_C2 + th];
        f32x16 z;
#pragma unroll
        for (int q = 0; q < 16; ++q) z[q] = ((const float*)tb4)[q];
        z = __builtin_amdgcn_mfma_f32_32x32x16_bf16(aw[0], hb[0], z, 0, 0, 0);
        z = __builtin_amdgcn_mfma_f32_32x32x16_bf16(aw[1], hb[1], z, 0, 0, 0);
        z = __builtin_amdgcn_mfma_f32_32x32x16_bf16(aw[2], hb[2], z, 0, 0, 0);
        z = __builtin_amdgcn_mfma_f32_32x32x16_bf16(aw[3], hb[3], z, 0, 0, 0);
        float p0 = 0.f, p1 = 0.f, p2 = 0.f, p3 = 0.f;
#pragma unroll
        for (int q = 0; q < 4; ++q) {
            p0 = fmaf(((const float*)w24)[q],    fmaxf(z[q],    0.f), p0);
            p1 = fmaf(((const float*)w24)[q+4],  fmaxf(z[q+4],  0.f), p1);
            p2 = fmaf(((const float*)w24)[q+8],  fmaxf(z[q+8],  0.f), p2);
            p3 = fmaf(((const float*)w24)[q+12], fmaxf(z[q+12], 0.f), p3);
        }
        float p = (p0 + p1) + (p2 + p3);
        p += __shfl_xor(p, 32);   // other r-half
        p += c2t;
        outv = (th == tsel) ? p : outv;
    }
    if (!hi) out[sbase + wave * 32 + ln31] = outv;   // coalesced 32-lane store
}

extern "C" void kernel_launch(void* const* d_in, const int* in_sizes, int n_in,
                              void* d_out, int out_size, void* d_ws, size_t ws_size,
                              hipStream_t stream) {
    const float* x       = (const float*)d_in[0];
    const int*   t       = (const int*)  d_in[1];
    const float* fw      = (const float*)d_in[2];
    const float* fb      = (const float*)d_in[3];
    const float* f_gamma = (const float*)d_in[4];
    const float* f_beta  = (const float*)d_in[5];
    const float* f_mean  = (const float*)d_in[6];
    const float* f_var   = (const float*)d_in[7];
    const float* tw1     = (const float*)d_in[8];
    const float* tb1     = (const float*)d_in[9];
    const float* t_gamma = (const float*)d_in[10];
    const float* t_beta  = (const float*)d_in[11];
    const float* t_mean  = (const float*)d_in[12];
    const float* t_var   = (const float*)d_in[13];
    const float* tw2     = (const float*)d_in[14];
    const float* tb2     = (const float*)d_in[15];

    float* ws   = (float*)d_ws;
    float* outp = (float*)d_out;
    const int B = in_sizes[0] / 128;   // 262144

    tarnet_pre<<<1, 256, 0, stream>>>(fw, fb, f_gamma, f_beta, f_mean, f_var,
                                      tw1, tb1, t_gamma, t_beta, t_mean, t_var,
                                      tw2, tb2, ws);
    x_stage_probe<<<B / 128, 256, 0, stream>>>(x, ws);
    tarnet_main<<<B / 128, 256, 0, stream>>>(x, t, ws, outp);
}

// Round 12
// 67.972 us; speedup vs baseline: 2.0038x; 1.1345x over previous
//
#include <hip/hip_runtime.h>
#include <hip/hip_bf16.h>
#include <cstdint>

#define EPS 1e-5f

typedef short bf16x8 __attribute__((ext_vector_type(8)));
typedef float f32x16 __attribute__((ext_vector_type(16)));
typedef unsigned int u32x4 __attribute__((ext_vector_type(4)));

// ws float-offsets
#define WS_TW1S 0        // 16384 ushort: chi-permuted GEMM2 A-frag layout
#define WS_FWQ  8192     // 8192 ushort: GEMM1 A-frag layout
#define WS_FBQ  12800    // 64 floats: [hi*32 + ht*16 + q]
#define WS_C2   12864    // 8 floats
#define WS_TB1A 12880    // 4096 ushort: [(th*2+hi)*32+r]*8 bias A-frags (z-GEMM K-slot)
#define WS_W2A  14928    // 2048 ushort: [((part*2+kt)*2+hi)*32+ln]*8 w2 A-frags (epi GEMM)
#define WS_H    1048576  // h buffer: 16 Mushort (32 MB), [(T*4+ks)*2+hi]*256 + ln31*8

static __device__ __forceinline__ unsigned short f2bf(float f) {
    unsigned int u = __float_as_uint(f);
    u += 0x7fffu + ((u >> 16) & 1u);   // RNE
    return (unsigned short)(u >> 16);
}
static __device__ __forceinline__ short f2bf_fast(float f) {
    __hip_bfloat16 b = __float2bfloat16(f);
    return __builtin_bit_cast(short, b);
}
static __device__ __forceinline__ unsigned pk_bf16(float lo, float hi) {
    unsigned l = (unsigned)(unsigned short)__builtin_bit_cast(unsigned short, __float2bfloat16(lo));
    unsigned h = (unsigned)(unsigned short)__builtin_bit_cast(unsigned short, __float2bfloat16(hi));
    return l | (h << 16);
}

// Fold BNs; emit frag-native tables.
// chi  (GEMM1->GEMM2): j = ht*32+qq*8+4h+m -> ks = ht*2+(qq>>1), slot = 8h+(qq&1)*4+m
// chi2 (z->epilogue):  r = (e&3) + 8*((e>>2)&1) + 16*kt + 4*hi  at slot s = 8*hi+e
__global__ void tarnet_pre(
    const float* __restrict__ fw, const float* __restrict__ fb,
    const float* __restrict__ f_gamma, const float* __restrict__ f_beta,
    const float* __restrict__ f_mean,  const float* __restrict__ f_var,
    const float* __restrict__ tw1, const float* __restrict__ tb1,
    const float* __restrict__ t_gamma, const float* __restrict__ t_beta,
    const float* __restrict__ t_mean,  const float* __restrict__ t_var,
    const float* __restrict__ tw2, const float* __restrict__ tb2,
    float* __restrict__ ws)
{
    __shared__ float fs[64], fsh[64];
    const int i = threadIdx.x;  // 256 threads
    if (i < 64) {
        float s = f_gamma[i] * rsqrtf(f_var[i] + EPS);
        fs[i]  = s;
        fsh[i] = f_beta[i] - f_mean[i] * s;
    }
    __syncthreads();

    unsigned short* tw1s_u = (unsigned short*)(ws + WS_TW1S);
    unsigned short* fwq_u  = (unsigned short*)(ws + WS_FWQ);
    unsigned short* tb1a_u = (unsigned short*)(ws + WS_TB1A);
    unsigned short* w2a_u  = (unsigned short*)(ws + WS_W2A);

    const int t = i >> 5, r = i & 31;
    const int idx = t * 32 + r;
    {
        float tsc  = t_gamma[idx] * rsqrtf(t_var[idx] + EPS);
        float tb1s = tb1[idx];
        for (int j = 0; j < 64; ++j) {
            float w = tw1[idx * 64 + j];
            tb1s += w * fsh[j];
            int ht = j >> 5, qq = (j >> 3) & 3, h = (j >> 2) & 1, m = j & 3;
            int ks = ht * 2 + (qq >> 1);
            int ep = (qq & 1) * 4 + m;
            tw1s_u[(((t*4 + ks)*2 + h)*32 + r)*8 + ep] = f2bf(w * fs[j]);
        }
        // TB1A: z-GEMM bias A-frag, slot0 of hi=0 only
        const int b0 = ((t*2 + 0)*32 + r)*8, b1 = ((t*2 + 1)*32 + r)*8;
        tb1a_u[b0] = f2bf(tb1s);
        for (int e = 1; e < 8; ++e) tb1a_u[b0 + e] = 0;
        for (int e = 0; e < 8; ++e) tb1a_u[b1 + e] = 0;
    }
    if (r == 0) {
        float a = tb2[t];
        for (int rr = 0; rr < 32; ++rr) {
            int id2 = t*32 + rr;
            float ts2 = t_gamma[id2] * rsqrtf(t_var[id2] + EPS);
            a += tw2[id2] * (t_beta[id2] - ts2 * t_mean[id2]);
        }
        ws[WS_C2 + t] = a;
    }
    {   // fw conversion, frag-native, parallel
        const int hc = i >> 2, kq = (i & 3) * 32;
        for (int kk = 0; kk < 32; ++kk) {
            const int k = kq + kk;
            const int ks = k >> 4, h = (k >> 3) & 1, jj = k & 7;
            fwq_u[(((ks*2 + h)*64) + hc)*8 + jj] = f2bf(fw[hc*128 + k]);
        }
    }
    if (i < 64) {
        int ht = i >> 5, r32 = i & 31;
        int q  = ((r32 >> 3) << 2) | (r32 & 3);
        int hq = (r32 >> 2) & 1;
        ws[WS_FBQ + hq*32 + ht*16 + q] = fb[i];
    }
    {   // W2A: epilogue A-frags, rows = th (<8), chi2 K-permuted, hi+lo parts
        const int ln = i & 31, hh = (i >> 5) & 1, kt = (i >> 6) & 1, part = i >> 7;
        const int base = (((part*2 + kt)*2 + hh)*32 + ln)*8;
        for (int e = 0; e < 8; ++e) {
            unsigned short v = 0;
            if (ln < 8) {
                const int rr = (e & 3) + 8*((e >> 2) & 1) + 16*kt + 4*hh;
                const int id2 = ln*32 + rr;
                float tsc = t_gamma[id2] * rsqrtf(t_var[id2] + EPS);
                float w = tw2[id2] * tsc;
                if (part == 0) v = f2bf(w);
                else {
                    float whi = __uint_as_float(((unsigned)f2bf(w)) << 16);
                    v = f2bf(w - whi);
                }
            }
            w2a_u[base + e] = v;
        }
    }
}

// ---- K1: GEMM1, DMA-staged x (global_load_lds f32, src pre-swizzled), no barriers ----
__global__ __launch_bounds__(256, 4) void tarnet_gemm1(
    const float* __restrict__ x, const float* __restrict__ ws)
{
    __shared__ uint4 xls[4096];   // 64 KB f32 tile, [row][chunk^(row&31)]
    const int tid  = threadIdx.x;
    const int wave = tid >> 6, lane = tid & 63;
    const int ln31 = lane & 31, hi = lane >> 5;

    const float* tile = x + (size_t)blockIdx.x * 16384;   // 128 rows x 128 f32

    // issue 16 fire-and-forget DMA per wave; wave w covers rows w*32..w*32+31
#pragma unroll
    for (int it = 0; it < 16; ++it) {
        const int row = wave*32 + it*2 + hi;
        const int gchunk = ln31 ^ (row & 31);
        const float* gp = tile + row*128 + gchunk*4;
        __builtin_amdgcn_global_load_lds(
            (const __attribute__((address_space(1))) void*)gp,
            (__attribute__((address_space(3))) void*)(xls + wave*1024 + it*64),
            16, 0, 0);
    }
    asm volatile("s_waitcnt vmcnt(0)" ::: "memory");
    __builtin_amdgcn_sched_barrier(0);

    const unsigned short* fwq_u = (const unsigned short*)(ws + WS_FWQ);
    const char* xl = (const char*)xls;
    const int r = wave*32 + ln31;   // this lane's sample row (own wave's region)

    f32x16 acc[2];
    {
        const float* fbq = ws + WS_FBQ;
#pragma unroll
        for (int ht = 0; ht < 2; ++ht)
#pragma unroll
            for (int q = 0; q < 16; ++q)
                acc[ht][q] = fbq[hi*32 + ht*16 + q];
    }
#pragma unroll
    for (int ks = 0; ks < 8; ++ks) {
        bf16x8 wa0 = *(const bf16x8*)(fwq_u + (((ks*2 + hi)*64) + ln31     )*8);
        bf16x8 wa1 = *(const bf16x8*)(fwq_u + (((ks*2 + hi)*64) + ln31 + 32)*8);
        const int c0 = (ks*4 + hi*2)     ^ ln31;   // (r&31)==ln31
        const int c1 = (ks*4 + hi*2 + 1) ^ ln31;
        float4 xa = *(const float4*)(xl + r*512 + c0*16);
        float4 xb = *(const float4*)(xl + r*512 + c1*16);
        bf16x8 xf;
        xf[0] = f2bf_fast(xa.x); xf[1] = f2bf_fast(xa.y);
        xf[2] = f2bf_fast(xa.z); xf[3] = f2bf_fast(xa.w);
        xf[4] = f2bf_fast(xb.x); xf[5] = f2bf_fast(xb.y);
        xf[6] = f2bf_fast(xb.z); xf[7] = f2bf_fast(xb.w);
        acc[0] = __builtin_amdgcn_mfma_f32_32x32x16_bf16(wa0, xf, acc[0], 0, 0, 0);
        acc[1] = __builtin_amdgcn_mfma_f32_32x32x16_bf16(wa1, xf, acc[1], 0, 0, 0);
    }

    // relu -> bf16 chi-pack -> store h in K2 B-frag-native layout (coalesced)
    unsigned short* h_u = (unsigned short*)(ws + WS_H);
    const int T = blockIdx.x*4 + wave;
    {
        unsigned w0[2][4], w1[2][4];
#pragma unroll
        for (int ht = 0; ht < 2; ++ht)
#pragma unroll
            for (int qq = 0; qq < 4; ++qq) {
                float a0 = fmaxf(acc[ht][qq*4+0], 0.f);
                float a1 = fmaxf(acc[ht][qq*4+1], 0.f);
                float a2 = fmaxf(acc[ht][qq*4+2], 0.f);
                float a3 = fmaxf(acc[ht][qq*4+3], 0.f);
                w0[ht][qq] = pk_bf16(a0, a1);
                w1[ht][qq] = pk_bf16(a2, a3);
            }
#pragma unroll
        for (int ks = 0; ks < 4; ++ks) {
            const int ht = ks >> 1, qa = (ks & 1) * 2;
            u32x4 wv = {w0[ht][qa], w1[ht][qa], w0[ht][qa+1], w1[ht][qa+1]};
            *(u32x4*)(h_u + ((T*4 + ks)*2 + hi)*256 + ln31*8) = wv;
        }
    }
}

// ---- K2: GEMM2 + MFMA epilogue, no LDS. 4 waves/block, 1 tile32/wave ----
__global__ __launch_bounds__(256, 3) void tarnet_gemm2(
    const int* __restrict__ t_arr, const float* __restrict__ ws,
    float* __restrict__ out)
{
    const int tid  = threadIdx.x;
    const int wave = tid >> 6, lane = tid & 63;
    const int ln31 = lane & 31, hi = lane >> 5;
    const int T = blockIdx.x*4 + wave;
    const int s0 = T*32;

    const unsigned short* h_u    = (const unsigned short*)(ws + WS_H);
    const unsigned short* tw1s_u = (const unsigned short*)(ws + WS_TW1S);
    const unsigned short* tb1a_u = (const unsigned short*)(ws + WS_TB1A);
    const unsigned short* w2a_u  = (const unsigned short*)(ws + WS_W2A);

    // h B-frags (coalesced 16B/lane)
    bf16x8 hb[4];
#pragma unroll
    for (int ks = 0; ks < 4; ++ks)
        hb[ks] = *(const bf16x8*)(h_u + ((T*4 + ks)*2 + hi)*256 + ln31*8);
    // constant-1 bias B-frag: slot0 (hi=0,e=0) = 1.0
    u32x4 hbv = { hi ? 0u : 0x3F80u, 0u, 0u, 0u };
    const bf16x8 hbias = __builtin_bit_cast(bf16x8, hbv);
    // w2 epilogue A-frags: [part][kt]
    bf16x8 w2f[4];
#pragma unroll
    for (int pk = 0; pk < 4; ++pk)
        w2f[pk] = *(const bf16x8*)(w2a_u + ((pk*2 + hi)*32 + ln31)*8);

    const int tsel = t_arr[s0 + ln31];
    float outv = 0.f;

#pragma unroll
    for (int th = 0; th < 8; ++th) {
        bf16x8 aw[4];
#pragma unroll
        for (int ks = 0; ks < 4; ++ks)
            aw[ks] = *(const bf16x8*)(tw1s_u + (((th*4 + ks)*2 + hi)*32 + ln31)*8);
        bf16x8 tba = *(const bf16x8*)(tb1a_u + ((th*2 + hi)*32 + ln31)*8);

        f32x16 z = {0.f};
        z = __builtin_amdgcn_mfma_f32_32x32x16_bf16(aw[0], hb[0], z, 0, 0, 0);
        z = __builtin_amdgcn_mfma_f32_32x32x16_bf16(aw[1], hb[1], z, 0, 0, 0);
        z = __builtin_amdgcn_mfma_f32_32x32x16_bf16(aw[2], hb[2], z, 0, 0, 0);
        z = __builtin_amdgcn_mfma_f32_32x32x16_bf16(aw[3], hb[3], z, 0, 0, 0);
        z = __builtin_amdgcn_mfma_f32_32x32x16_bf16(tba,  hbias, z, 0, 0, 0);

        // chi2 pack: zb[kt] = relu(z[8kt .. 8kt+7]) in order
        bf16x8 zb[2];
#pragma unroll
        for (int kt = 0; kt < 2; ++kt) {
            u32x4 wv;
#pragma unroll
            for (int wd = 0; wd < 4; ++wd)
                wv[wd] = pk_bf16(fmaxf(z[8*kt + 2*wd], 0.f),
                                 fmaxf(z[8*kt + 2*wd + 1], 0.f));
            zb[kt] = __builtin_bit_cast(bf16x8, wv);
        }
        // epilogue GEMM: d[row=th'][col=sample] = sum_r w2*relu(z)
        f32x16 d = {0.f};
        d = __builtin_amdgcn_mfma_f32_32x32x16_bf16(w2f[0], zb[0], d, 0, 0, 0);
        d = __builtin_amdgcn_mfma_f32_32x32x16_bf16(w2f[1], zb[1], d, 0, 0, 0);
        d = __builtin_amdgcn_mfma_f32_32x32x16_bf16(w2f[2], zb[0], d, 0, 0, 0);
        d = __builtin_amdgcn_mfma_f32_32x32x16_bf16(w2f[3], zb[1], d, 0, 0, 0);

        float cand  = d[th & 3];                 // row th lives at reg th&3, half th>>2
        float other = __shfl_xor(cand, 32);
        float val   = (hi == (th >> 2)) ? cand : other;
        outv = (th == tsel) ? val : outv;
    }
    outv += ws[WS_C2 + tsel];   // c2 f32-exact
    if (!hi) out[s0 + ln31] = outv;
}

extern "C" void kernel_launch(void* const* d_in, const int* in_sizes, int n_in,
                              void* d_out, int out_size, void* d_ws, size_t ws_size,
                              hipStream_t stream) {
    const float* x       = (const float*)d_in[0];
    const int*   t       = (const int*)  d_in[1];
    const float* fw      = (const float*)d_in[2];
    const float* fb      = (const float*)d_in[3];
    const float* f_gamma = (const float*)d_in[4];
    const float* f_beta  = (const float*)d_in[5];
    const float* f_mean  = (const float*)d_in[6];
    const float* f_var   = (const float*)d_in[7];
    const float* tw1     = (const float*)d_in[8];
    const float* tb1     = (const float*)d_in[9];
    const float* t_gamma = (const float*)d_in[10];
    const float* t_beta  = (const float*)d_in[11];
    const float* t_mean  = (const float*)d_in[12];
    const float* t_var   = (const float*)d_in[13];
    const float* tw2     = (const float*)d_in[14];
    const float* tb2     = (const float*)d_in[15];

    float* ws   = (float*)d_ws;
    float* outp = (float*)d_out;
    const int B = in_sizes[0] / 128;   // 262144

    tarnet_pre<<<1, 256, 0, stream>>>(fw, fb, f_gamma, f_beta, f_mean, f_var,
                                      tw1, tb1, t_gamma, t_beta, t_mean, t_var,
                                      tw2, tb2, ws);
    tarnet_gemm1<<<B / 128, 256, 0, stream>>>(x, ws);
    tarnet_gemm2<<<B / 128, 256, 0, stream>>>(t, ws, outp);
}